// Round 5
// baseline (473.301 us; speedup 1.0000x reference)
//
#include <hip/hip_runtime.h>
#include <hip/hip_bf16.h>

#define RELS 8
#define HDD 128
#define NH 4
#define STILES 8

typedef __attribute__((ext_vector_type(8))) short bf16x8;
typedef __attribute__((ext_vector_type(4))) float f32x4;
typedef unsigned short u16;

__device__ __forceinline__ u16 f2b(float v){
  union { float f; unsigned u; } x; x.f = v;
  unsigned r = x.u + 0x7fffu + ((x.u >> 16) & 1u);
  return (u16)(r >> 16);
}
__device__ __forceinline__ float b2f(u16 h){
  union { unsigned u; float f; } x; x.u = ((unsigned)h) << 16; return x.f;
}

// ---- combo: prep_w | prep_feat | hist, split by block ranges ----
__global__ void k_combo(const float* __restrict__ wsrc, const float* __restrict__ wqual,
                        const float* __restrict__ bsrc, const float* __restrict__ bqual,
                        u16* __restrict__ Wt, float* __restrict__ biasc,
                        const float* __restrict__ feat, const float* __restrict__ qual,
                        u16* __restrict__ featb, u16* __restrict__ qualb, int total,
                        const int* __restrict__ dst, const int* __restrict__ rt,
                        int* __restrict__ deg, int* __restrict__ rcnt, int E,
                        int B0, int B1){
  int b = blockIdx.x, t = threadIdx.x;
  if (b < B0){
    int g = b*256 + t;
    if (g < RELS*HDD*HDD){
      int r = g >> 14, rem = g & 16383, n = rem >> 7, k = rem & 127;
      float v = (k < 64) ? wsrc[r*8192 + k*128 + n] : wqual[r*8192 + (k-64)*128 + n];
      Wt[g] = f2b(v);
    } else {
      int bb = g - RELS*HDD*HDD;
      if (bb < RELS*HDD) biasc[bb] = bsrc[bb] + bqual[bb];
    }
  } else if (b < B0 + B1){
    int g = ((b - B0)*256 + t) * 8;
    const float* sp; u16* dp;
    if (g < total){ sp = feat; dp = featb; }
    else { g -= total; if (g >= total) return; sp = qual; dp = qualb; }
    float4 a = *(const float4*)(sp + g);
    float4 c = *(const float4*)(sp + g + 4);
    union { u16 h[8]; uint4 v; } o;
    o.h[0]=f2b(a.x); o.h[1]=f2b(a.y); o.h[2]=f2b(a.z); o.h[3]=f2b(a.w);
    o.h[4]=f2b(c.x); o.h[5]=f2b(c.y); o.h[6]=f2b(c.z); o.h[7]=f2b(c.w);
    *(uint4*)(dp + g) = o.v;
  } else {
    __shared__ int lh[RELS];
    if (t < RELS) lh[t] = 0;
    __syncthreads();
    int e = (b - B0 - B1)*256 + t;
    if (e < E){
      atomicAdd(&deg[dst[e]], 1);
      atomicAdd(&lh[rt[e]], 1);
    }
    __syncthreads();
    if (t < RELS && lh[t]) atomicAdd(&rcnt[t], lh[t]);
  }
}

// ---- 3-phase exclusive scan over deg[N] -> offD ----
__global__ void k_scan_a(const int* __restrict__ deg, int* __restrict__ offD,
                         int* __restrict__ bsums, int N){
  __shared__ int s[256];
  int t = threadIdx.x, i = blockIdx.x*256 + t;
  int v = (i < N) ? deg[i] : 0;
  s[t] = v; __syncthreads();
  for (int off=1; off<256; off<<=1){
    int x = (t >= off) ? s[t-off] : 0;
    __syncthreads();
    s[t] += x;
    __syncthreads();
  }
  if (i < N) offD[i] = s[t] - v;
  if (t == 255) bsums[blockIdx.x] = s[255];
}

__global__ void k_scan_b(const int* __restrict__ bsums, int* __restrict__ bsums_sc,
                         int* __restrict__ offD, const int* __restrict__ rcnt,
                         int* __restrict__ roff, int* __restrict__ rcur,
                         int NBLK, int N){
  __shared__ int s[512];
  int t = threadIdx.x;
  int v = (t < NBLK) ? bsums[t] : 0;
  s[t] = v; __syncthreads();
  for (int off=1; off<512; off<<=1){
    int x = (t >= off) ? s[t-off] : 0;
    __syncthreads();
    s[t] += x;
    __syncthreads();
  }
  if (t < NBLK) bsums_sc[t] = s[t] - v;
  if (t == NBLK-1) offD[N] = s[t];
  if (t == 0){
    int a = 0;
    for (int r=0;r<RELS;r++){ roff[r]=a; rcur[r]=a; a += rcnt[r]; }
    roff[RELS] = a;
  }
}

__global__ void k_scan_c(int* __restrict__ offD, const int* __restrict__ bsums_sc, int N){
  int i = blockIdx.x*256 + threadIdx.x;
  if (i < N) offD[i] += bsums_sc[i >> 8];
}

// ---- scatter: dst-order srcD; rel-order srcR/nidR/posR (pre-gathered) ----
__global__ void k_scatter(const int* __restrict__ dst, const int* __restrict__ rt,
                          const int* __restrict__ src, const int* __restrict__ nid,
                          const int* __restrict__ offD, int* __restrict__ curD,
                          int* __restrict__ rcur,
                          int* __restrict__ srcD, int* __restrict__ srcR,
                          int* __restrict__ nidR, int* __restrict__ posR, int E){
  __shared__ int lh[RELS], lb[RELS];
  int t = threadIdx.x;
  if (t < RELS) lh[t] = 0;
  __syncthreads();
  int e = blockIdx.x*256 + t;
  int r = 0, rank = 0, pd = 0, sv = 0;
  if (e < E){
    int d = dst[e];
    sv = src[e];
    pd = offD[d] + atomicAdd(&curD[d], 1);
    srcD[pd] = sv;
    r = rt[e];
    rank = atomicAdd(&lh[r], 1);
  }
  __syncthreads();
  if (t < RELS && lh[t] > 0) lb[t] = atomicAdd(&rcur[t], lh[t]);
  __syncthreads();
  if (e < E){
    int pr = lb[r] + rank;
    srcR[pr] = sv;
    nidR[pr] = nid[e];
    posR[pr] = pd;
  }
}

// ---- fused projection + leaky_relu + attn dot -> scoreD[posR,4], MFMA ----
// 8 tiles of 64 edges per block; depth-2 register prefetch + double-buffered
// LDS so tile t+2's gathers are in flight during tiles t,t+1 compute.
__global__ __launch_bounds__(256) void k_score(
    const u16* __restrict__ featb, const u16* __restrict__ qualb,
    const u16* __restrict__ Wt, const float* __restrict__ biasc,
    const float* __restrict__ attn,
    const int* __restrict__ srcR, const int* __restrict__ nidR,
    const int* __restrict__ posR, const int* __restrict__ roff,
    float* __restrict__ scoreD){
  __shared__ u16 As[2][64*128];
  __shared__ int pos_s[2][64];
  int t = threadIdx.x;

  // per-thread segment resolve (uniform -> scalarized)
  int bid = blockIdx.x;
  int r = -1, base = 0, cntR = 0;
  {
    int acc = 0;
    int prev = roff[0];
    #pragma unroll
    for (int rr=0; rr<RELS; rr++){
      int nxt = roff[rr+1];
      int c = nxt - prev;
      int nb = (c + STILES*64 - 1) / (STILES*64);
      if (r < 0 && bid < acc + nb){
        int ch = bid - acc;
        r = rr; base = prev + ch*STILES*64; cntR = min(STILES*64, c - ch*STILES*64);
      }
      acc += nb;
      prev = nxt;
    }
  }
  if (r < 0) return;
  int Tact = (cntR + 63) >> 6;

  int mloc = t >> 2, part = t & 3;

  // per-wave B fragments: head w = t>>6, cols w*32 .. w*32+31
  int lane = t & 63, w = t >> 6;
  int lr = lane & 15, lq = lane >> 4;
  const u16* wbase = Wt + r*16384 + (w*32)*128;
  bf16x8 bfrag[2][4];
  #pragma unroll
  for (int nt=0; nt<2; nt++)
    #pragma unroll
    for (int kt=0; kt<4; kt++)
      bfrag[nt][kt] = *(const bf16x8*)(wbase + (nt*16 + lr)*128 + kt*32 + lq*8);

  float attn_c0, attn_c1, bias_c0, bias_c1;
  {
    int c0 = w*32 + lr, c1 = w*32 + 16 + lr;
    attn_c0 = attn[r*128 + c0]; attn_c1 = attn[r*128 + c1];
    bias_c0 = biasc[r*128 + c0]; bias_c1 = biasc[r*128 + c1];
  }

  // depth-2 prefetch registers
  uint4 pre[2][4]; int prePos[2];
  auto issue_tile = [&](int tt, int s){
    int eloc = tt*64 + mloc;
    if (tt < Tact && eloc < cntR){
      int gi = base + eloc;
      if (part == 0) prePos[s] = posR[gi];
      const u16* rowp = (part < 2) ? (featb + (long long)srcR[gi]*64)
                                   : (qualb + (long long)nidR[gi]*64);
      const uint4* pv = (const uint4*)(rowp + (part & 1)*32);
      pre[s][0]=pv[0]; pre[s][1]=pv[1]; pre[s][2]=pv[2]; pre[s][3]=pv[3];
    } else {
      uint4 z = {0,0,0,0};
      pre[s][0]=z; pre[s][1]=z; pre[s][2]=z; pre[s][3]=z;
      prePos[s] = -1;
    }
  };

  issue_tile(0, 0);
  issue_tile(1, 1);
  for (int tt=0; tt<Tact; ++tt){
    int p = tt & 1;
    uint4* As_v = (uint4*)As[p];
    // drain prefetch stage p (loads issued 2 tiles ago) into LDS
    #pragma unroll
    for (int i=0;i<4;i++){
      int c = part*4 + i;
      As_v[mloc*16 + (c ^ (mloc & 7))] = pre[p][i];
    }
    if (part == 0) pos_s[p][mloc] = prePos[p];
    // refill stage p with tile tt+2 gathers
    issue_tile(tt+2, p);
    __syncthreads();

    f32x4 acc[4][2];
    #pragma unroll
    for (int mt=0; mt<4; mt++){ acc[mt][0]=(f32x4){0,0,0,0}; acc[mt][1]=(f32x4){0,0,0,0}; }
    #pragma unroll
    for (int mt=0; mt<4; mt++){
      #pragma unroll
      for (int kt=0; kt<4; kt++){
        bf16x8 af = *(const bf16x8*)&As[p][(mt*16 + lr)*128 + (((kt*4 + lq) ^ (lr & 7))*8)];
        acc[mt][0] = __builtin_amdgcn_mfma_f32_16x16x32_bf16(af, bfrag[0][kt], acc[mt][0], 0, 0, 0);
        acc[mt][1] = __builtin_amdgcn_mfma_f32_16x16x32_bf16(af, bfrag[1][kt], acc[mt][1], 0, 0, 0);
      }
    }

    // epilogue: + bias, leaky_relu, * attn, reduce over the 32 cols of head w
    float sh[4][4];
    #pragma unroll
    for (int mt=0; mt<4; mt++)
      #pragma unroll
      for (int i=0; i<4; i++){
        float x0 = acc[mt][0][i] + bias_c0;
        x0 = (x0 > 0.f) ? x0 : 0.2f*x0;
        float x1 = acc[mt][1][i] + bias_c1;
        x1 = (x1 > 0.f) ? x1 : 0.2f*x1;
        sh[mt][i] = x0*attn_c0 + x1*attn_c1;
      }
    #pragma unroll
    for (int mt=0; mt<4; mt++)
      #pragma unroll
      for (int i=0; i<4; i++){
        float v = sh[mt][i];
        v += __shfl_xor(v, 1);
        v += __shfl_xor(v, 2);
        v += __shfl_xor(v, 4);
        v += __shfl_xor(v, 8);
        sh[mt][i] = v;
      }
    if (lr == 0){
      #pragma unroll
      for (int mt=0; mt<4; mt++)
        #pragma unroll
        for (int i=0; i<4; i++){
          int m = mt*16 + lq*4 + i;
          int pd = pos_s[p][m];
          if (pd >= 0) scoreD[(long long)pd*4 + w] = sh[mt][i];
        }
    }
  }
}

// ---- fused softmax + aggregation: wave per node, lane = feat dim ----
// chunk-of-64 softmax (lane=edge) with LDS broadcast of weights into the
// lane=feature aggregation loop. exp computed once per edge total.
__global__ __launch_bounds__(256) void k_agg(
    const int* __restrict__ offD, const int* __restrict__ srcD,
    const float* __restrict__ scoreD,
    const u16* __restrict__ featb, float* __restrict__ out, int N){
  __shared__ float ps[4][64][4];
  __shared__ int   ss[4][64];
  int wv = threadIdx.x >> 6, lane = threadIdx.x & 63;
  int node = blockIdx.x*4 + wv;
  if (node >= N) return;
  int s0 = offD[node], s1 = offD[node+1];
  int deg = s1 - s0;
  float a0=0.f, a1=0.f, a2=0.f, a3=0.f;
  if (deg > 0){
    // pass 1: exact per-head max over the segment
    float m0=-1e30f, m1=-1e30f, m2=-1e30f, m3=-1e30f;
    for (int c=0; c<deg; c+=64){
      int j = c + lane;
      if (j < deg){
        float4 sc = *(const float4*)&scoreD[(long long)(s0+j)*4];
        m0=fmaxf(m0,sc.x); m1=fmaxf(m1,sc.y); m2=fmaxf(m2,sc.z); m3=fmaxf(m3,sc.w);
      }
    }
    #pragma unroll
    for (int off=1; off<64; off<<=1){
      m0=fmaxf(m0,__shfl_xor(m0,off));
      m1=fmaxf(m1,__shfl_xor(m1,off));
      m2=fmaxf(m2,__shfl_xor(m2,off));
      m3=fmaxf(m3,__shfl_xor(m3,off));
    }
    // pass 2: exp + denom + weighted aggregation per 64-edge chunk
    float d0=0.f,d1=0.f,d2=0.f,d3=0.f;
    for (int c=0; c<deg; c+=64){
      int j = c + lane;
      float p0=0.f,p1=0.f,p2=0.f,p3=0.f; int sv=0;
      if (j < deg){
        float4 sc = *(const float4*)&scoreD[(long long)(s0+j)*4];
        sv = srcD[s0+j];
        p0=__expf(sc.x-m0); p1=__expf(sc.y-m1); p2=__expf(sc.z-m2); p3=__expf(sc.w-m3);
      }
      d0+=p0; d1+=p1; d2+=p2; d3+=p3;
      float4 pv = { p0, p1, p2, p3 };
      *(float4*)&ps[wv][lane][0] = pv;
      ss[wv][lane] = sv;
      __builtin_amdgcn_wave_barrier();
      int cnt = min(64, deg - c);
      #pragma unroll 4
      for (int e=0; e<cnt; e++){
        float4 pe = *(const float4*)&ps[wv][e][0];
        float fv = b2f(featb[(long long)ss[wv][e]*64 + lane]);
        a0 += pe.x*fv; a1 += pe.y*fv; a2 += pe.z*fv; a3 += pe.w*fv;
      }
      __builtin_amdgcn_wave_barrier();
    }
    #pragma unroll
    for (int off=1; off<64; off<<=1){
      d0+=__shfl_xor(d0,off); d1+=__shfl_xor(d1,off);
      d2+=__shfl_xor(d2,off); d3+=__shfl_xor(d3,off);
    }
    a0 *= 1.f/d0; a1 *= 1.f/d1; a2 *= 1.f/d2; a3 *= 1.f/d3;
  }
  float* op = out + (long long)node*256;
  op[lane]       = a0;
  op[64 + lane]  = a1;
  op[128 + lane] = a2;
  op[192 + lane] = a3;
}

extern "C" void kernel_launch(void* const* d_in, const int* in_sizes, int n_in,
                              void* d_out, int out_size, void* d_ws, size_t ws_size,
                              hipStream_t stream) {
  const float* feat  = (const float*)d_in[0];
  const float* qual  = (const float*)d_in[1];
  const float* wsrc  = (const float*)d_in[2];
  const float* bsrc  = (const float*)d_in[3];
  const float* wqual = (const float*)d_in[4];
  const float* bqual = (const float*)d_in[5];
  const float* attn  = (const float*)d_in[6];
  const int* src = (const int*)d_in[7];
  const int* dst = (const int*)d_in[8];
  const int* rt  = (const int*)d_in[9];
  const int* nid = (const int*)d_in[10];
  const int E = in_sizes[7];
  const int N = in_sizes[0] / 64;
  float* out = (float*)d_out;

  char* p = (char*)d_ws;
  auto alloc = [&](size_t bytes) -> void* {
    void* q = (void*)p;
    p += (bytes + 255) & ~(size_t)255;
    return q;
  };
  float* scoreD  = (float*)alloc((size_t)E*4*4);
  u16*  featb    = (u16*)  alloc((size_t)N*64*2);
  u16*  qualb    = (u16*)  alloc((size_t)N*64*2);
  u16*  Wt       = (u16*)  alloc((size_t)RELS*HDD*HDD*2);
  float* biasc   = (float*)alloc((size_t)RELS*HDD*4);
  int*  srcD     = (int*)  alloc((size_t)E*4);
  int*  srcR     = (int*)  alloc((size_t)E*4);
  int*  nidR     = (int*)  alloc((size_t)E*4);
  int*  posR     = (int*)  alloc((size_t)E*4);
  int*  offD     = (int*)  alloc((size_t)(N+1)*4);
  int*  bsums    = (int*)  alloc(4096);
  int*  bsums_sc = (int*)  alloc(4096);
  char* zbase = p;
  int*  deg      = (int*)  alloc((size_t)N*4);
  int*  curD     = (int*)  alloc((size_t)N*4);
  int*  rcnt     = (int*)  alloc(32);
  int*  roff     = (int*)  alloc(64);
  int*  rcur     = (int*)  alloc(32);
  size_t zbytes = (size_t)(p - zbase);

  hipMemsetAsync(zbase, 0, zbytes, stream);

  // combo: prep_w | prep_feat | hist
  int total = N*64;
  int totw = RELS*HDD*HDD + RELS*HDD;
  int B0 = (totw + 255)/256;
  int B1 = ((2*total)/8 + 255)/256;
  int B2 = (E + 255)/256;
  k_combo<<<B0+B1+B2, 256, 0, stream>>>(wsrc, wqual, bsrc, bqual, Wt, biasc,
                                        feat, qual, featb, qualb, total,
                                        dst, rt, deg, rcnt, E, B0, B1);
  // scan + scatter
  int NBLK = (N + 255)/256;
  k_scan_a<<<NBLK, 256, 0, stream>>>(deg, offD, bsums, N);
  k_scan_b<<<1, 512, 0, stream>>>(bsums, bsums_sc, offD, rcnt, roff, rcur, NBLK, N);
  k_scan_c<<<NBLK, 256, 0, stream>>>(offD, bsums_sc, N);
  k_scatter<<<B2, 256, 0, stream>>>(dst, rt, src, nid, offD, curD, rcur, srcD, srcR, nidR, posR, E);
  // fused score -> dst-sorted scoreD
  int NBS = (E + STILES*64 - 1)/(STILES*64) + RELS;
  k_score<<<NBS, 256, 0, stream>>>(featb, qualb, Wt, biasc, attn, srcR, nidR, posR, roff, scoreD);
  // fused softmax + aggregate
  k_agg<<<(N + 3)/4, 256, 0, stream>>>(offD, srcD, scoreD, featb, out, N);
}

// Round 6
// 421.517 us; speedup vs baseline: 1.1229x; 1.1229x over previous
//
#include <hip/hip_runtime.h>
#include <hip/hip_bf16.h>

#define RELS 8
#define HDD 128
#define NH 4
#define STILES 4

typedef __attribute__((ext_vector_type(8))) short bf16x8;
typedef __attribute__((ext_vector_type(4))) float f32x4;
typedef unsigned short u16;

__device__ __forceinline__ u16 f2b(float v){
  union { float f; unsigned u; } x; x.f = v;
  unsigned r = x.u + 0x7fffu + ((x.u >> 16) & 1u);
  return (u16)(r >> 16);
}
__device__ __forceinline__ float b2f(u16 h){
  union { unsigned u; float f; } x; x.u = ((unsigned)h) << 16; return x.f;
}

// ---- combo: prep_w | prep_feat | hist, split by block ranges ----
__global__ void k_combo(const float* __restrict__ wsrc, const float* __restrict__ wqual,
                        const float* __restrict__ bsrc, const float* __restrict__ bqual,
                        u16* __restrict__ Wt, float* __restrict__ biasc,
                        const float* __restrict__ feat, const float* __restrict__ qual,
                        u16* __restrict__ featb, u16* __restrict__ qualb, int total,
                        const int* __restrict__ dst, const int* __restrict__ rt,
                        int* __restrict__ deg, int* __restrict__ rcnt, int E,
                        int B0, int B1){
  int b = blockIdx.x, t = threadIdx.x;
  if (b < B0){
    int g = b*256 + t;
    if (g < RELS*HDD*HDD){
      int r = g >> 14, rem = g & 16383, n = rem >> 7, k = rem & 127;
      float v = (k < 64) ? wsrc[r*8192 + k*128 + n] : wqual[r*8192 + (k-64)*128 + n];
      Wt[g] = f2b(v);
    } else {
      int bb = g - RELS*HDD*HDD;
      if (bb < RELS*HDD) biasc[bb] = bsrc[bb] + bqual[bb];
    }
  } else if (b < B0 + B1){
    int g = ((b - B0)*256 + t) * 8;
    const float* sp; u16* dp;
    if (g < total){ sp = feat; dp = featb; }
    else { g -= total; if (g >= total) return; sp = qual; dp = qualb; }
    float4 a = *(const float4*)(sp + g);
    float4 c = *(const float4*)(sp + g + 4);
    union { u16 h[8]; uint4 v; } o;
    o.h[0]=f2b(a.x); o.h[1]=f2b(a.y); o.h[2]=f2b(a.z); o.h[3]=f2b(a.w);
    o.h[4]=f2b(c.x); o.h[5]=f2b(c.y); o.h[6]=f2b(c.z); o.h[7]=f2b(c.w);
    *(uint4*)(dp + g) = o.v;
  } else {
    __shared__ int lh[RELS];
    if (t < RELS) lh[t] = 0;
    __syncthreads();
    int e = (b - B0 - B1)*256 + t;
    if (e < E){
      atomicAdd(&deg[dst[e]], 1);
      atomicAdd(&lh[rt[e]], 1);
    }
    __syncthreads();
    if (t < RELS && lh[t]) atomicAdd(&rcnt[t], lh[t]);
  }
}

// ---- 3-phase exclusive scan over deg[N] -> offD ----
__global__ void k_scan_a(const int* __restrict__ deg, int* __restrict__ offD,
                         int* __restrict__ bsums, int N){
  __shared__ int s[256];
  int t = threadIdx.x, i = blockIdx.x*256 + t;
  int v = (i < N) ? deg[i] : 0;
  s[t] = v; __syncthreads();
  for (int off=1; off<256; off<<=1){
    int x = (t >= off) ? s[t-off] : 0;
    __syncthreads();
    s[t] += x;
    __syncthreads();
  }
  if (i < N) offD[i] = s[t] - v;
  if (t == 255) bsums[blockIdx.x] = s[255];
}

__global__ void k_scan_b(const int* __restrict__ bsums, int* __restrict__ bsums_sc,
                         int* __restrict__ offD, const int* __restrict__ rcnt,
                         int* __restrict__ roff, int* __restrict__ rcur,
                         int NBLK, int N){
  __shared__ int s[512];
  int t = threadIdx.x;
  int v = (t < NBLK) ? bsums[t] : 0;
  s[t] = v; __syncthreads();
  for (int off=1; off<512; off<<=1){
    int x = (t >= off) ? s[t-off] : 0;
    __syncthreads();
    s[t] += x;
    __syncthreads();
  }
  if (t < NBLK) bsums_sc[t] = s[t] - v;
  if (t == NBLK-1) offD[N] = s[t];
  if (t == 0){
    int a = 0;
    for (int r=0;r<RELS;r++){ roff[r]=a; rcur[r]=a; a += rcnt[r]; }
    roff[RELS] = a;
  }
}

__global__ void k_scan_c(int* __restrict__ offD, const int* __restrict__ bsums_sc, int N){
  int i = blockIdx.x*256 + threadIdx.x;
  if (i < N) offD[i] += bsums_sc[i >> 8];
}

// ---- scatter: dst-order srcD; rel-order srcR/nidR/posR (pre-gathered) ----
__global__ void k_scatter(const int* __restrict__ dst, const int* __restrict__ rt,
                          const int* __restrict__ src, const int* __restrict__ nid,
                          const int* __restrict__ offD, int* __restrict__ curD,
                          int* __restrict__ rcur,
                          int* __restrict__ srcD, int* __restrict__ srcR,
                          int* __restrict__ nidR, int* __restrict__ posR, int E){
  __shared__ int lh[RELS], lb[RELS];
  int t = threadIdx.x;
  if (t < RELS) lh[t] = 0;
  __syncthreads();
  int e = blockIdx.x*256 + t;
  int r = 0, rank = 0, pd = 0, sv = 0;
  if (e < E){
    int d = dst[e];
    sv = src[e];
    pd = offD[d] + atomicAdd(&curD[d], 1);
    srcD[pd] = sv;
    r = rt[e];
    rank = atomicAdd(&lh[r], 1);
  }
  __syncthreads();
  if (t < RELS && lh[t] > 0) lb[t] = atomicAdd(&rcur[t], lh[t]);
  __syncthreads();
  if (e < E){
    int pr = lb[r] + rank;
    srcR[pr] = sv;
    nidR[pr] = nid[e];
    posR[pr] = pd;
  }
}

// ---- fused projection + leaky_relu + attn dot -> scoreD[posR,4], MFMA ----
// 4 tiles of 64 edges per block. All tile indices preloaded into registers
// (fully unrolled, constant indexing — avoids the scratch-spill of r5), so
// the steady-state prefetch is a single-hop row gather hidden behind one
// tile of MFMA+epilogue. Depth-1 register prefetch, double-buffered LDS.
__global__ __launch_bounds__(256) void k_score(
    const u16* __restrict__ featb, const u16* __restrict__ qualb,
    const u16* __restrict__ Wt, const float* __restrict__ biasc,
    const float* __restrict__ attn,
    const int* __restrict__ srcR, const int* __restrict__ nidR,
    const int* __restrict__ posR, const int* __restrict__ roff,
    float* __restrict__ scoreD){
  __shared__ u16 As[2][64*128];
  __shared__ int pos_s[2][64];
  int t = threadIdx.x;

  // per-thread segment resolve (uniform -> scalarized)
  int bid = blockIdx.x;
  int r = -1, base = 0, cntR = 0;
  {
    int acc = 0;
    int prev = roff[0];
    #pragma unroll
    for (int rr=0; rr<RELS; rr++){
      int nxt = roff[rr+1];
      int c = nxt - prev;
      int nb = (c + STILES*64 - 1) / (STILES*64);
      if (r < 0 && bid < acc + nb){
        int ch = bid - acc;
        r = rr; base = prev + ch*STILES*64; cntR = min(STILES*64, c - ch*STILES*64);
      }
      acc += nb;
      prev = nxt;
    }
  }
  if (r < 0) return;
  int Tact = (cntR + 63) >> 6;

  int mloc = t >> 2, part = t & 3;
  int lane = t & 63, w = t >> 6;
  int lr = lane & 15, lq = lane >> 4;

  // per-wave B fragments: head w, cols w*32 .. w*32+31
  const u16* wbase = Wt + r*16384 + (w*32)*128;
  bf16x8 bfrag[2][4];
  #pragma unroll
  for (int nt=0; nt<2; nt++)
    #pragma unroll
    for (int kt=0; kt<4; kt++)
      bfrag[nt][kt] = *(const bf16x8*)(wbase + (nt*16 + lr)*128 + kt*32 + lq*8);

  float attn_c0, attn_c1, bias_c0, bias_c1;
  {
    int c0 = w*32 + lr, c1 = w*32 + 16 + lr;
    attn_c0 = attn[r*128 + c0]; attn_c1 = attn[r*128 + c1];
    bias_c0 = biasc[r*128 + c0]; bias_c1 = biasc[r*128 + c1];
  }

  // ---- preload ALL tile indices into registers (constant-indexed) ----
  const u16* basep = (part < 2) ? featb : qualb;
  int halfoff = (part & 1)*32;
  int myidx[STILES], mypos[STILES];
  #pragma unroll
  for (int tt=0; tt<STILES; tt++){
    int eloc = tt*64 + mloc;
    bool v = (eloc < cntR);
    int gi = base + eloc;
    myidx[tt] = v ? ((part < 2) ? srcR[gi] : nidR[gi]) : -1;
    mypos[tt] = v ? posR[gi] : -1;
  }

  uint4 pre[4];
  auto fetch = [&](int idxval){
    if (idxval >= 0){
      const uint4* pv = (const uint4*)(basep + (long long)idxval*64 + halfoff);
      pre[0]=pv[0]; pre[1]=pv[1]; pre[2]=pv[2]; pre[3]=pv[3];
    } else {
      uint4 z = {0,0,0,0};
      pre[0]=z; pre[1]=z; pre[2]=z; pre[3]=z;
    }
  };

  fetch(myidx[0]);
  #pragma unroll
  for (int tt=0; tt<STILES; tt++){
    if (tt >= Tact) break;
    const int p = tt & 1;
    uint4* As_v = (uint4*)As[p];
    // drain prefetch into LDS (XOR-swizzled 16B chunks)
    #pragma unroll
    for (int i=0;i<4;i++){
      int c = part*4 + i;
      As_v[mloc*16 + (c ^ (mloc & 7))] = pre[i];
    }
    if (part == 0) pos_s[p][mloc] = mypos[tt];
    // issue next tile's single-hop gather (index already in register)
    if (tt+1 < STILES) fetch(myidx[tt+1]);
    __syncthreads();

    f32x4 acc[4][2];
    #pragma unroll
    for (int mt=0; mt<4; mt++){ acc[mt][0]=(f32x4){0,0,0,0}; acc[mt][1]=(f32x4){0,0,0,0}; }
    #pragma unroll
    for (int mt=0; mt<4; mt++){
      #pragma unroll
      for (int kt=0; kt<4; kt++){
        bf16x8 af = *(const bf16x8*)&As[p][(mt*16 + lr)*128 + (((kt*4 + lq) ^ (lr & 7))*8)];
        acc[mt][0] = __builtin_amdgcn_mfma_f32_16x16x32_bf16(af, bfrag[0][kt], acc[mt][0], 0, 0, 0);
        acc[mt][1] = __builtin_amdgcn_mfma_f32_16x16x32_bf16(af, bfrag[1][kt], acc[mt][1], 0, 0, 0);
      }
    }

    // epilogue: + bias, leaky_relu, * attn, reduce over the 32 cols of head w
    float sh[4][4];
    #pragma unroll
    for (int mt=0; mt<4; mt++)
      #pragma unroll
      for (int i=0; i<4; i++){
        float x0 = acc[mt][0][i] + bias_c0;
        x0 = (x0 > 0.f) ? x0 : 0.2f*x0;
        float x1 = acc[mt][1][i] + bias_c1;
        x1 = (x1 > 0.f) ? x1 : 0.2f*x1;
        sh[mt][i] = x0*attn_c0 + x1*attn_c1;
      }
    #pragma unroll
    for (int mt=0; mt<4; mt++)
      #pragma unroll
      for (int i=0; i<4; i++){
        float v = sh[mt][i];
        v += __shfl_xor(v, 1);
        v += __shfl_xor(v, 2);
        v += __shfl_xor(v, 4);
        v += __shfl_xor(v, 8);
        sh[mt][i] = v;
      }
    if (lr == 0){
      #pragma unroll
      for (int mt=0; mt<4; mt++)
        #pragma unroll
        for (int i=0; i<4; i++){
          int m = mt*16 + lq*4 + i;
          int pd = pos_s[p][m];
          if (pd >= 0) scoreD[(long long)pd*4 + w] = sh[mt][i];
        }
    }
  }
}

// ---- fused softmax + aggregation: wave per node, lane = feat dim ----
__global__ __launch_bounds__(256) void k_agg(
    const int* __restrict__ offD, const int* __restrict__ srcD,
    const float* __restrict__ scoreD,
    const u16* __restrict__ featb, float* __restrict__ out, int N){
  __shared__ float ps[4][64][4];
  __shared__ int   ss[4][64];
  int wv = threadIdx.x >> 6, lane = threadIdx.x & 63;
  int node = blockIdx.x*4 + wv;
  if (node >= N) return;
  int s0 = offD[node], s1 = offD[node+1];
  int deg = s1 - s0;
  float a0=0.f, a1=0.f, a2=0.f, a3=0.f;
  if (deg > 0){
    float m0=-1e30f, m1=-1e30f, m2=-1e30f, m3=-1e30f;
    for (int c=0; c<deg; c+=64){
      int j = c + lane;
      if (j < deg){
        float4 sc = *(const float4*)&scoreD[(long long)(s0+j)*4];
        m0=fmaxf(m0,sc.x); m1=fmaxf(m1,sc.y); m2=fmaxf(m2,sc.z); m3=fmaxf(m3,sc.w);
      }
    }
    #pragma unroll
    for (int off=1; off<64; off<<=1){
      m0=fmaxf(m0,__shfl_xor(m0,off));
      m1=fmaxf(m1,__shfl_xor(m1,off));
      m2=fmaxf(m2,__shfl_xor(m2,off));
      m3=fmaxf(m3,__shfl_xor(m3,off));
    }
    float d0=0.f,d1=0.f,d2=0.f,d3=0.f;
    for (int c=0; c<deg; c+=64){
      int j = c + lane;
      float p0=0.f,p1=0.f,p2=0.f,p3=0.f; int sv=0;
      if (j < deg){
        float4 sc = *(const float4*)&scoreD[(long long)(s0+j)*4];
        sv = srcD[s0+j];
        p0=__expf(sc.x-m0); p1=__expf(sc.y-m1); p2=__expf(sc.z-m2); p3=__expf(sc.w-m3);
      }
      d0+=p0; d1+=p1; d2+=p2; d3+=p3;
      float4 pv = { p0, p1, p2, p3 };
      *(float4*)&ps[wv][lane][0] = pv;
      ss[wv][lane] = sv;
      __builtin_amdgcn_wave_barrier();
      int cnt = min(64, deg - c);
      #pragma unroll 4
      for (int e=0; e<cnt; e++){
        float4 pe = *(const float4*)&ps[wv][e][0];
        float fv = b2f(featb[(long long)ss[wv][e]*64 + lane]);
        a0 += pe.x*fv; a1 += pe.y*fv; a2 += pe.z*fv; a3 += pe.w*fv;
      }
      __builtin_amdgcn_wave_barrier();
    }
    #pragma unroll
    for (int off=1; off<64; off<<=1){
      d0+=__shfl_xor(d0,off); d1+=__shfl_xor(d1,off);
      d2+=__shfl_xor(d2,off); d3+=__shfl_xor(d3,off);
    }
    a0 *= 1.f/d0; a1 *= 1.f/d1; a2 *= 1.f/d2; a3 *= 1.f/d3;
  }
  float* op = out + (long long)node*256;
  op[lane]       = a0;
  op[64 + lane]  = a1;
  op[128 + lane] = a2;
  op[192 + lane] = a3;
}

extern "C" void kernel_launch(void* const* d_in, const int* in_sizes, int n_in,
                              void* d_out, int out_size, void* d_ws, size_t ws_size,
                              hipStream_t stream) {
  const float* feat  = (const float*)d_in[0];
  const float* qual  = (const float*)d_in[1];
  const float* wsrc  = (const float*)d_in[2];
  const float* bsrc  = (const float*)d_in[3];
  const float* wqual = (const float*)d_in[4];
  const float* bqual = (const float*)d_in[5];
  const float* attn  = (const float*)d_in[6];
  const int* src = (const int*)d_in[7];
  const int* dst = (const int*)d_in[8];
  const int* rt  = (const int*)d_in[9];
  const int* nid = (const int*)d_in[10];
  const int E = in_sizes[7];
  const int N = in_sizes[0] / 64;
  float* out = (float*)d_out;

  char* p = (char*)d_ws;
  auto alloc = [&](size_t bytes) -> void* {
    void* q = (void*)p;
    p += (bytes + 255) & ~(size_t)255;
    return q;
  };
  float* scoreD  = (float*)alloc((size_t)E*4*4);
  u16*  featb    = (u16*)  alloc((size_t)N*64*2);
  u16*  qualb    = (u16*)  alloc((size_t)N*64*2);
  u16*  Wt       = (u16*)  alloc((size_t)RELS*HDD*HDD*2);
  float* biasc   = (float*)alloc((size_t)RELS*HDD*4);
  int*  srcD     = (int*)  alloc((size_t)E*4);
  int*  srcR     = (int*)  alloc((size_t)E*4);
  int*  nidR     = (int*)  alloc((size_t)E*4);
  int*  posR     = (int*)  alloc((size_t)E*4);
  int*  offD     = (int*)  alloc((size_t)(N+1)*4);
  int*  bsums    = (int*)  alloc(4096);
  int*  bsums_sc = (int*)  alloc(4096);
  char* zbase = p;
  int*  deg      = (int*)  alloc((size_t)N*4);
  int*  curD     = (int*)  alloc((size_t)N*4);
  int*  rcnt     = (int*)  alloc(32);
  int*  roff     = (int*)  alloc(64);
  int*  rcur     = (int*)  alloc(32);
  size_t zbytes = (size_t)(p - zbase);

  hipMemsetAsync(zbase, 0, zbytes, stream);

  // combo: prep_w | prep_feat | hist
  int total = N*64;
  int totw = RELS*HDD*HDD + RELS*HDD;
  int B0 = (totw + 255)/256;
  int B1 = ((2*total)/8 + 255)/256;
  int B2 = (E + 255)/256;
  k_combo<<<B0+B1+B2, 256, 0, stream>>>(wsrc, wqual, bsrc, bqual, Wt, biasc,
                                        feat, qual, featb, qualb, total,
                                        dst, rt, deg, rcnt, E, B0, B1);
  // scan + scatter
  int NBLK = (N + 255)/256;
  k_scan_a<<<NBLK, 256, 0, stream>>>(deg, offD, bsums, N);
  k_scan_b<<<1, 512, 0, stream>>>(bsums, bsums_sc, offD, rcnt, roff, rcur, NBLK, N);
  k_scan_c<<<NBLK, 256, 0, stream>>>(offD, bsums_sc, N);
  k_scatter<<<B2, 256, 0, stream>>>(dst, rt, src, nid, offD, curD, rcur, srcD, srcR, nidR, posR, E);
  // fused score -> dst-sorted scoreD
  int NBS = (E + STILES*64 - 1)/(STILES*64) + RELS;
  k_score<<<NBS, 256, 0, stream>>>(featb, qualb, Wt, biasc, attn, srcR, nidR, posR, roff, scoreD);
  // fused softmax + aggregate
  k_agg<<<(N + 3)/4, 256, 0, stream>>>(offD, srcD, scoreD, featb, out, N);
}